// Round 10
// baseline (196.151 us; speedup 1.0000x reference)
//
#include <hip/hip_runtime.h>
#include <math.h>

#define BS 32
#define NQ 900
#define NC 91
#define NT 30
#define NJ (BS*NT)            // 960
#define C3_SZ ((size_t)BS*NQ*NJ)
#define NROWS (BS*NQ)         // 28800

#define LT 960                // block size (15 waves)
#define LWAVES (LT/64)        // 15
#define NCOSTBLK 224          // 32 LSA + 224 writers = 256 blocks, all resident
#define MAXROWS 132           // ceil(28800/224)=129
#define KPL 15                // Dijkstra: columns per lane (64*15 >= 900)

__device__ __forceinline__ float fast_rcp(float x) { return __builtin_amdgcn_rcpf(x); }

struct SharedLSA {
    float  cst[NT * NQ];      // 108000 B  cst[r*NQ+q]
    int    p[NQ + 1];
    int    way[NQ + 1];
    int    rows[NT];
    int    tl[NT];
    float4 tbox[NT];
    float  rminv[NT];         // greedy: per-row min value
    int    rminc[NT];         // greedy: per-row argmin column (1-based)
    int    aflag[NT + 1];     // greedy: row assigned?
};
struct SharedCost {
    float  prob[MAXROWS][NC]; // full softmax rows: 132*91*4 = 48048 B
    float4 pbx[MAXROWS];      // pred boxes for the chunk
};

__device__ __forceinline__ float cost_elem(
    float pcx, float pcy, float pw, float ph,
    float px0, float py0, float px1, float py1, float area_a,
    float pr,
    float tcx, float tcy, float tw, float th,
    float tx0, float ty0, float tx1, float ty1, float area_b)
{
    float cost_bbox = fabsf(pcx - tcx) + fabsf(pcy - tcy) + fabsf(pw - tw) + fabsf(ph - th);
    float ix0 = fmaxf(px0, tx0), iy0 = fmaxf(py0, ty0);
    float ix1 = fminf(px1, tx1), iy1 = fminf(py1, ty1);
    float inter = fmaxf(ix1 - ix0, 0.f) * fmaxf(iy1 - iy0, 0.f);
    float uni = area_a + area_b - inter;
    float iou = inter * fast_rcp(uni);
    float ex0 = fminf(px0, tx0), ey0 = fminf(py0, ty0);
    float ex1 = fmaxf(px1, tx1), ey1 = fmaxf(py1, ty1);
    float encl = fmaxf(ex1 - ex0, 0.f) * fmaxf(ey1 - ey0, 0.f);
    float giou = iou - (encl - uni) * fast_rcp(encl);
    return 5.0f * cost_bbox - pr - 2.0f * giou + 3.0f;   // 5*bbox + (1-p) + 2*(1-giou)
}

// writer path: store the full prob row (ea*rs / ec*rs)
__device__ __forceinline__ void softmax_prob_row(const float* __restrict__ lrow, int lane,
                                                 float* __restrict__ prob)
{
    float a = (lane < NC)      ? lrow[lane]      : -1e30f;
    float c = (lane + 64 < NC) ? lrow[lane + 64] : -1e30f;
    float m = fmaxf(a, c);
    for (int off = 32; off; off >>= 1) m = fmaxf(m, __shfl_xor(m, off));
    float ea = (lane < NC)      ? __expf(a - m) : 0.f;
    float ec = (lane + 64 < NC) ? __expf(c - m) : 0.f;
    float s = ea + ec;
    for (int off = 32; off; off >>= 1) s += __shfl_xor(s, off);
    float rs = fast_rcp(s);
    if (lane < NC)      prob[lane]      = ea * rs;
    if (lane + 64 < NC) prob[lane + 64] = ec * rs;
}

__global__ __launch_bounds__(LT) void fused_kernel(
    const float* __restrict__ logits,   // (NROWS, NC)
    const float* __restrict__ pboxes,   // (NROWS, 4)
    const int*   __restrict__ tlabels,  // (NJ)
    const float* __restrict__ tboxes,   // (NJ, 4)
    float* __restrict__ out,            // (NROWS, NJ)
    float* __restrict__ outp,           // (BS, NT)
    float* __restrict__ outt)           // (BS, NT)
{
    __shared__ union { SharedLSA l; SharedCost c; } sm;
    const int t = threadIdx.x;
    const int wv = t >> 6;
    const int lane = t & 63;

    if (blockIdx.x < BS) {
        // ================= LSA block for batch b =================
        const int b = blockIdx.x;
        const float* lg  = logits + (size_t)b * NQ * NC;
        const float* pbx = pboxes + (size_t)b * NQ * 4;

        if (t < NT) {
            sm.l.tl[t] = tlabels[b * NT + t];
            sm.l.tbox[t] = ((const float4*)tboxes)[b * NT + t];
        }
        for (int j = t; j <= NQ; j += LT) { sm.l.p[j] = 0; sm.l.way[j] = 0; }
        __syncthreads();

        // fused phase A+B (verified r5): per row softmax reduce + 30 cost elems
        for (int q = wv; q < NQ; q += LWAVES) {
            const float* lrow = lg + (size_t)q * NC;
            float a = (lane < NC)      ? lrow[lane]      : -1e30f;
            float c = (lane + 64 < NC) ? lrow[lane + 64] : -1e30f;
            float m = fmaxf(a, c);
            for (int off = 32; off; off >>= 1) m = fmaxf(m, __shfl_xor(m, off));
            float ea = (lane < NC)      ? __expf(a - m) : 0.f;
            float ec = (lane + 64 < NC) ? __expf(c - m) : 0.f;
            float s = ea + ec;
            for (int off = 32; off; off >>= 1) s += __shfl_xor(s, off);
            float rs = fast_rcp(s);

            int lbl = sm.l.tl[lane < NT ? lane : 0];
            float pa = __shfl(ea, lbl & 63);
            float pc = __shfl(ec, lbl & 63);
            if (lane < NT) {
                float pr = ((lbl < 64) ? pa : pc) * rs;
                float4 pb = ((const float4*)pbx)[q];
                float pcx = pb.x, pcy = pb.y, pw = pb.z, ph = pb.w;
                float px0 = pcx - 0.5f*pw, py0 = pcy - 0.5f*ph;
                float px1 = pcx + 0.5f*pw, py1 = pcy + 0.5f*ph;
                float area_a = pw * ph;
                float4 tb = sm.l.tbox[lane];
                float tcx = tb.x, tcy = tb.y, tw = tb.z, th = tb.w;
                float tx0 = tcx - 0.5f*tw, ty0 = tcy - 0.5f*th;
                float tx1 = tcx + 0.5f*tw, ty1 = tcy + 0.5f*th;
                float area_b = tw * th;
                sm.l.cst[lane * NQ + q] =
                    cost_elem(pcx, pcy, pw, ph, px0, py0, px1, py1, area_a,
                              pr, tcx, tcy, tw, th, tx0, ty0, tx1, ty1, area_b);
            }
        }
        __syncthreads();

        // greedy init: per-row min + argmin (wave-per-row, coalesced LDS reads)
        for (int r = wv; r < NT; r += LWAVES) {
            float bv = 1e30f; int bi = 1 << 20;
            for (int j = lane; j < NQ; j += 64) {
                float v = sm.l.cst[r * NQ + j];
                if (v < bv) { bv = v; bi = j; }           // ascending j: first-min per lane
            }
            for (int off = 32; off; off >>= 1) {
                float ov = __shfl_xor(bv, off);
                int   oi = __shfl_xor(bi, off);
                if (ov < bv || (ov == bv && oi < bi)) { bv = ov; bi = oi; }
            }
            if (lane == 0) { sm.l.rminv[r] = bv; sm.l.rminc[r] = bi + 1; }
        }
        __syncthreads();

        // ====== wave 0: greedy claim + register-dual single-wave Dijkstra ======
        if (wv == 0) {
            // parallel greedy claim: row r wins col c iff no j<r picked c (verbatim r5)
            {
                int r = lane;
                int myc = (r < NT) ? sm.l.rminc[r] : -1;
                bool win = (r < NT);
                for (int j = 0; j < NT; ++j) {
                    int cj = __shfl(myc, j);
                    if (j < r && cj == myc) win = false;
                }
                if (r < NT) {
                    sm.l.aflag[r + 1] = win ? 1 : 0;
                    if (win) sm.l.p[myc] = r + 1;
                }
            }

            // Register-resident duals: lane r holds u[r+1]; vvr[k] = v[1+lane+64k].
            // Same step semantics as r9/r5: strict-< minv update, smallest-column
            // tie-break, identical delta/u/v bookkeeping (doubles).
            double ur = (lane < NT) ? (double)sm.l.rminv[lane] : 0.0;
            double vvr[KPL], minv[KPL];
            #pragma unroll
            for (int k = 0; k < KPL; ++k) vvr[k] = 0.0;

            for (int i = 1; i <= NT; ++i) {
                if (sm.l.aflag[i]) continue;               // uniform LDS read
                #pragma unroll
                for (int k = 0; k < KPL; ++k) minv[k] = 1e18;
                unsigned usedm = 0;
                unsigned rowmask = 1u << (i - 1);          // rows on the path (incl. i)
                int i0 = i, j0 = 0, j1f = 0;
                for (;;) {
                    double u_i0 = __shfl(ur, i0 - 1);      // broadcast from owner lane
                    double best = 1e18; int bestc = 1 << 20;
                    #pragma unroll
                    for (int k = 0; k < KPL; ++k) {
                        int col = 1 + lane + (k << 6);
                        if (col <= NQ && !((usedm >> k) & 1u)) {
                            double cur = (double)sm.l.cst[(i0 - 1) * NQ + (col - 1)]
                                         - u_i0 - vvr[k];
                            if (cur < minv[k]) { minv[k] = cur; sm.l.way[col] = j0; }
                            if (minv[k] < best) { best = minv[k]; bestc = col; }
                        }
                    }
                    for (int off = 32; off; off >>= 1) {   // single-wave butterfly
                        double ov = __shfl_xor(best, off);
                        int    oc = __shfl_xor(bestc, off);
                        if (ov < best || (ov == best && oc < bestc)) { best = ov; bestc = oc; }
                    }
                    double delta = best;
                    int    j1    = bestc;
                    // rows on path += delta (same set+timing as u[i], u[p[used col]] += delta)
                    if (lane < NT && ((rowmask >> lane) & 1u)) ur += delta;
                    #pragma unroll
                    for (int k = 0; k < KPL; ++k) {
                        int col = 1 + lane + (k << 6);
                        if (col <= NQ) {
                            if ((usedm >> k) & 1u) vvr[k] -= delta;
                            else                   minv[k] -= delta;
                        }
                    }
                    if (((j1 - 1) & 63) == lane)           // claim j1 (after unused update)
                        usedm |= (1u << ((j1 - 1) >> 6));
                    int pj1 = sm.l.p[j1];                  // uniform broadcast read
                    if (pj1 == 0) { j1f = j1; break; }
                    rowmask |= 1u << (pj1 - 1);
                    i0 = pj1; j0 = j1;
                }
                if (lane == 0) {                           // augment walk (serial, short)
                    int j0w = j1f;
                    while (j0w) {
                        int jp = sm.l.way[j0w];
                        sm.l.p[j0w] = (jp == 0) ? i : sm.l.p[jp];
                        j0w = jp;
                    }
                }
            }
        }
        __syncthreads();

        if (t >= 1 && t <= NQ && sm.l.p[t] > 0) sm.l.rows[sm.l.p[t] - 1] = t - 1;
        __syncthreads();

        // parallel rank-based stable argsort (keys distinct) + output, wave 0
        if (wv == 0) {
            int k = lane;
            int key = (k < NT) ? sm.l.rows[k] : 0x7fffffff;
            int rank = 0;
            for (int j = 0; j < NT; ++j) {
                int kj = __shfl(key, j);
                if (kj < key) ++rank;
            }
            if (k < NT) {
                outp[b * NT + rank] = (float)key;
                outt[b * NT + rank] = (float)k;
            }
        }
    } else {
        // ================= C3 writer block (verified round-5 path) =================
        const int cb = blockIdx.x - BS;                 // 0..223
        const int r0 = (int)(((long long)cb * NROWS) / NCOSTBLK);
        const int r1 = (int)(((long long)(cb + 1) * NROWS) / NCOSTBLK);
        const int nrows = r1 - r0;

        for (int rr = wv; rr < nrows; rr += LWAVES)
            softmax_prob_row(logits + (size_t)(r0 + rr) * NC, lane, sm.c.prob[rr]);
        for (int rr = t; rr < nrows; rr += LT)
            sm.c.pbx[rr] = ((const float4*)pboxes)[r0 + rr];

        const int   lbl = tlabels[t];
        const float4 tb = ((const float4*)tboxes)[t];
        const float tcx = tb.x, tcy = tb.y, tw = tb.z, th = tb.w;
        const float tx0 = tcx - 0.5f*tw, ty0 = tcy - 0.5f*th;
        const float tx1 = tcx + 0.5f*tw, ty1 = tcy + 0.5f*th;
        const float area_b = tw * th;
        __syncthreads();

        float* op = out + (size_t)r0 * NJ + t;
        #pragma unroll 2
        for (int rr = 0; rr < nrows; ++rr) {
            float pr = sm.c.prob[rr][lbl];
            float4 pb = sm.c.pbx[rr];
            float pcx = pb.x, pcy = pb.y, pw = pb.z, ph = pb.w;
            float px0 = pcx - 0.5f*pw, py0 = pcy - 0.5f*ph;
            float px1 = pcx + 0.5f*pw, py1 = pcy + 0.5f*ph;
            float area_a = pw * ph;
            float v = cost_elem(pcx, pcy, pw, ph, px0, py0, px1, py1, area_a,
                                pr, tcx, tcy, tw, th, tx0, ty0, tx1, ty1, area_b);
            __builtin_nontemporal_store(v, op);
            op += NJ;
        }
    }
}

extern "C" void kernel_launch(void* const* d_in, const int* in_sizes, int n_in,
                              void* d_out, int out_size, void* d_ws, size_t ws_size,
                              hipStream_t stream) {
    const float* logits  = (const float*)d_in[0];
    const float* pboxes  = (const float*)d_in[1];
    const int*   tlabels = (const int*)d_in[2];
    const float* tboxes  = (const float*)d_in[3];
    float* out = (float*)d_out;

    fused_kernel<<<BS + NCOSTBLK, LT, 0, stream>>>(
        logits, pboxes, tlabels, tboxes,
        out, out + C3_SZ, out + C3_SZ + (size_t)BS * NT);
}

// Round 11
// 182.333 us; speedup vs baseline: 1.0758x; 1.0758x over previous
//
#include <hip/hip_runtime.h>
#include <math.h>

#define BS 32
#define NQ 900
#define NC 91
#define NT 30
#define NJ (BS*NT)            // 960
#define C3_SZ ((size_t)BS*NQ*NJ)
#define NROWS (BS*NQ)         // 28800

#define LT 960                // block size (15 waves)
#define LWAVES (LT/64)        // 15
#define NCOSTBLK 224          // 32 LSA + 224 writers = 256 blocks, all resident
#define MAXROWS 132           // ceil(28800/224)=129

__device__ __forceinline__ float fast_rcp(float x) { return __builtin_amdgcn_rcpf(x); }

struct SharedLSA {
    float  cst[NT * NQ];      // 108000 B  cst[r*NQ+q]
    double u[NT + 1];
    int    p[NQ + 1];
    int    way[NQ + 1];
    double red_v[LWAVES];
    int    red_i[LWAVES];
    int    rows[NT];
    int    tl[NT];
    float4 tbox[NT];
    float  part_v[LWAVES][NT]; // per-wave row-min partials
    int    part_c[LWAVES][NT];
    float  rminv[NT];         // greedy: per-row min value
    int    rminc[NT];         // greedy: per-row argmin column (1-based)
    int    aflag[NT + 1];     // greedy: row assigned?
};
struct SharedCost {
    float  prob[MAXROWS][NC]; // full softmax rows: 132*91*4 = 48048 B
    float4 pbx[MAXROWS];      // pred boxes for the chunk
};

__device__ __forceinline__ float cost_elem(
    float pcx, float pcy, float pw, float ph,
    float px0, float py0, float px1, float py1, float area_a,
    float pr,
    float tcx, float tcy, float tw, float th,
    float tx0, float ty0, float tx1, float ty1, float area_b)
{
    float cost_bbox = fabsf(pcx - tcx) + fabsf(pcy - tcy) + fabsf(pw - tw) + fabsf(ph - th);
    float ix0 = fmaxf(px0, tx0), iy0 = fmaxf(py0, ty0);
    float ix1 = fminf(px1, tx1), iy1 = fminf(py1, ty1);
    float inter = fmaxf(ix1 - ix0, 0.f) * fmaxf(iy1 - iy0, 0.f);
    float uni = area_a + area_b - inter;
    float iou = inter * fast_rcp(uni);
    float ex0 = fminf(px0, tx0), ey0 = fminf(py0, ty0);
    float ex1 = fmaxf(px1, tx1), ey1 = fmaxf(py1, ty1);
    float encl = fmaxf(ex1 - ex0, 0.f) * fmaxf(ey1 - ey0, 0.f);
    float giou = iou - (encl - uni) * fast_rcp(encl);
    return 5.0f * cost_bbox - pr - 2.0f * giou + 3.0f;   // 5*bbox + (1-p) + 2*(1-giou)
}

// writer path: store the full prob row (ea*rs / ec*rs)
__device__ __forceinline__ void softmax_prob_row(const float* __restrict__ lrow, int lane,
                                                 float* __restrict__ prob)
{
    float a = (lane < NC)      ? lrow[lane]      : -1e30f;
    float c = (lane + 64 < NC) ? lrow[lane + 64] : -1e30f;
    float m = fmaxf(a, c);
    for (int off = 32; off; off >>= 1) m = fmaxf(m, __shfl_xor(m, off));
    float ea = (lane < NC)      ? __expf(a - m) : 0.f;
    float ec = (lane + 64 < NC) ? __expf(c - m) : 0.f;
    float s = ea + ec;
    for (int off = 32; off; off >>= 1) s += __shfl_xor(s, off);
    float rs = fast_rcp(s);
    if (lane < NC)      prob[lane]      = ea * rs;
    if (lane + 64 < NC) prob[lane + 64] = ec * rs;
}

__global__ __launch_bounds__(LT) void fused_kernel(
    const float* __restrict__ logits,   // (NROWS, NC)
    const float* __restrict__ pboxes,   // (NROWS, 4)
    const int*   __restrict__ tlabels,  // (NJ)
    const float* __restrict__ tboxes,   // (NJ, 4)
    float* __restrict__ out,            // (NROWS, NJ)
    float* __restrict__ outp,           // (BS, NT)
    float* __restrict__ outt)           // (BS, NT)
{
    __shared__ union { SharedLSA l; SharedCost c; } sm;
    const int t = threadIdx.x;
    const int wv = t >> 6;
    const int lane = t & 63;

    if (blockIdx.x < BS) {
        // ================= LSA block for batch b =================
        const int b = blockIdx.x;
        const float* lg  = logits + (size_t)b * NQ * NC;
        const float* pbx = pboxes + (size_t)b * NQ * 4;

        if (t < NT) {
            sm.l.tl[t] = tlabels[b * NT + t];
            sm.l.tbox[t] = ((const float4*)tboxes)[b * NT + t];
        }
        for (int j = t; j <= NQ; j += LT) { sm.l.p[j] = 0; sm.l.way[j] = 0; }
        __syncthreads();

        // ---- fused A+B+rowmin: branch-minimized, ILP-2, hoisted invariants ----
        const int  myr   = (lane < NT) ? lane : 0;
        const int  lbl   = sm.l.tl[myr];
        const int  lblL  = lbl & 63;
        const bool lblHi = (lbl >= 64);
        const float4 tb  = sm.l.tbox[myr];
        const float tcx = tb.x, tcy = tb.y, tw = tb.z, th = tb.w;
        const float tx0 = tcx - 0.5f*tw, ty0 = tcy - 0.5f*th;
        const float tx1 = tcx + 0.5f*tw, ty1 = tcy + 0.5f*th;
        const float area_b = tw * th;
        float runv = 1e30f; int runc = 1 << 20;   // per-lane row-min (row = lane)

        #pragma unroll 2
        for (int q = wv; q < NQ; q += LWAVES) {
            const float* lrow = lg + (size_t)q * NC;
            float a = (lane < NC)      ? lrow[lane]      : -1e30f;
            float c = (lane + 64 < NC) ? lrow[lane + 64] : -1e30f;
            float m = fmaxf(a, c);
            for (int off = 32; off; off >>= 1) m = fmaxf(m, __shfl_xor(m, off));
            float ea = (lane < NC)      ? __expf(a - m) : 0.f;
            float ec = (lane + 64 < NC) ? __expf(c - m) : 0.f;
            float s = ea + ec;
            for (int off = 32; off; off >>= 1) s += __shfl_xor(s, off);
            float rs = fast_rcp(s);
            float pa = __shfl(ea, lblL);
            float pc = __shfl(ec, lblL);
            float pr = (lblHi ? pc : pa) * rs;

            float4 pb = ((const float4*)pbx)[q];
            float pcx = pb.x, pcy = pb.y, pw = pb.z, ph = pb.w;
            float px0 = pcx - 0.5f*pw, py0 = pcy - 0.5f*ph;
            float px1 = pcx + 0.5f*pw, py1 = pcy + 0.5f*ph;
            float area_a = pw * ph;
            float v = cost_elem(pcx, pcy, pw, ph, px0, py0, px1, py1, area_a,
                                pr, tcx, tcy, tw, th, tx0, ty0, tx1, ty1, area_b);
            if (lane < NT) {
                sm.l.cst[lane * NQ + q] = v;
                if (v < runv) { runv = v; runc = q; }   // ascending q: first-min
            }
        }
        if (lane < NT) { sm.l.part_v[wv][lane] = runv; sm.l.part_c[wv][lane] = runc; }
        __syncthreads();

        // combine per-wave partials -> rminv/rminc (smallest-col tie-break,
        // identical to the old 64-lane butterfly semantics)
        if (wv == 0 && lane < NT) {
            float bv = 1e30f; int bc = 1 << 20;
            #pragma unroll
            for (int w = 0; w < LWAVES; ++w) {
                float pv = sm.l.part_v[w][lane];
                int   pcc = sm.l.part_c[w][lane];
                if (pv < bv || (pv == bv && pcc < bc)) { bv = pv; bc = pcc; }
            }
            sm.l.rminv[lane] = bv; sm.l.rminc[lane] = bc + 1;
        }
        __syncthreads();

        // parallel greedy claim (wave 0): row r wins col c iff no j<r picked c.
        if (wv == 0) {
            int r = lane;
            int myc = (r < NT) ? sm.l.rminc[r] : -1;
            bool win = (r < NT);
            for (int j = 0; j < NT; ++j) {
                int cj = __shfl(myc, j);
                if (j < r && cj == myc) win = false;
            }
            if (r < NT) {
                sm.l.u[r + 1] = (double)sm.l.rminv[r];
                sm.l.aflag[r + 1] = win ? 1 : 0;
                if (win) sm.l.p[myc] = r + 1;
            }
        }
        double v_t = 0.0;
        __syncthreads();

        // ---- JV Dijkstra only for unassigned rows (verified 15-wave core) ----
        for (int i = 1; i <= NT; ++i) {
            if (sm.l.aflag[i]) continue;                   // uniform branch
            double minv_t = 1e18;
            bool used_t = (t == 0);
            int p_t = (t == 0) ? i : ((t <= NQ) ? sm.l.p[t] : 0);
            int i0 = i, j0 = 0, j1f = 0;
            for (;;) {
                double u_i0 = sm.l.u[i0];
                double cand; int ci;
                if (t >= 1 && t <= NQ && !used_t) {
                    double cur = ((double)sm.l.cst[(i0 - 1) * NQ + (t - 1)] - u_i0) - v_t;
                    if (cur < minv_t) { minv_t = cur; sm.l.way[t] = j0; }
                    cand = minv_t; ci = t;
                } else { cand = 1e18; ci = 1 << 20; }
                for (int off = 32; off; off >>= 1) {
                    double ov = __shfl_xor(cand, off);
                    int    oi = __shfl_xor(ci, off);
                    if (ov < cand || (ov == cand && oi < ci)) { cand = ov; ci = oi; }
                }
                if (lane == 0) { sm.l.red_v[wv] = cand; sm.l.red_i[wv] = ci; }
                __syncthreads();                                   // (A)
                double rv; int ri;
                if (lane < LWAVES) { rv = sm.l.red_v[lane]; ri = sm.l.red_i[lane]; }
                else               { rv = 1e18;             ri = 1 << 20; }
                for (int off = 8; off; off >>= 1) {
                    double ov = __shfl_xor(rv, off);
                    int    oi = __shfl_xor(ri, off);
                    if (ov < rv || (ov == rv && oi < ri)) { rv = ov; ri = oi; }
                }
                double delta = __shfl(rv, 0);
                int    j1    = __shfl(ri, 0);
                if (used_t) { v_t -= delta; sm.l.u[p_t] += delta; }
                else if (t >= 1 && t <= NQ) minv_t -= delta;
                if (t == j1) { used_t = true; p_t = sm.l.p[j1]; }
                int pj1 = sm.l.p[j1];
                __syncthreads();                                   // (B)
                if (pj1 == 0) { j1f = j1; break; }
                i0 = pj1; j0 = j1;
            }
            if (t == 0) {
                int j0w = j1f;
                while (j0w) {
                    int jp = sm.l.way[j0w];
                    sm.l.p[j0w] = (jp == 0) ? i : sm.l.p[jp];
                    j0w = jp;
                }
            }
            __syncthreads();                                       // (C)
        }
        if (t >= 1 && t <= NQ && sm.l.p[t] > 0) sm.l.rows[sm.l.p[t] - 1] = t - 1;
        __syncthreads();

        // parallel rank-based stable argsort (keys distinct) + output, wave 0
        if (wv == 0) {
            int k = lane;
            int key = (k < NT) ? sm.l.rows[k] : 0x7fffffff;
            int rank = 0;
            for (int j = 0; j < NT; ++j) {
                int kj = __shfl(key, j);
                if (kj < key) ++rank;
            }
            if (k < NT) {
                outp[b * NT + rank] = (float)key;
                outt[b * NT + rank] = (float)k;
            }
        }
    } else {
        // ================= C3 writer block (verified round-5 path) =================
        const int cb = blockIdx.x - BS;                 // 0..223
        const int r0 = (int)(((long long)cb * NROWS) / NCOSTBLK);
        const int r1 = (int)(((long long)(cb + 1) * NROWS) / NCOSTBLK);
        const int nrows = r1 - r0;

        #pragma unroll 2
        for (int rr = wv; rr < nrows; rr += LWAVES)
            softmax_prob_row(logits + (size_t)(r0 + rr) * NC, lane, sm.c.prob[rr]);
        for (int rr = t; rr < nrows; rr += LT)
            sm.c.pbx[rr] = ((const float4*)pboxes)[r0 + rr];

        const int   lbl = tlabels[t];
        const float4 tb = ((const float4*)tboxes)[t];
        const float tcx = tb.x, tcy = tb.y, tw = tb.z, th = tb.w;
        const float tx0 = tcx - 0.5f*tw, ty0 = tcy - 0.5f*th;
        const float tx1 = tcx + 0.5f*tw, ty1 = tcy + 0.5f*th;
        const float area_b = tw * th;
        __syncthreads();

        float* op = out + (size_t)r0 * NJ + t;
        #pragma unroll 2
        for (int rr = 0; rr < nrows; ++rr) {
            float pr = sm.c.prob[rr][lbl];
            float4 pb = sm.c.pbx[rr];
            float pcx = pb.x, pcy = pb.y, pw = pb.z, ph = pb.w;
            float px0 = pcx - 0.5f*pw, py0 = pcy - 0.5f*ph;
            float px1 = pcx + 0.5f*pw, py1 = pcy + 0.5f*ph;
            float area_a = pw * ph;
            float v = cost_elem(pcx, pcy, pw, ph, px0, py0, px1, py1, area_a,
                                pr, tcx, tcy, tw, th, tx0, ty0, tx1, ty1, area_b);
            __builtin_nontemporal_store(v, op);
            op += NJ;
        }
    }
}

extern "C" void kernel_launch(void* const* d_in, const int* in_sizes, int n_in,
                              void* d_out, int out_size, void* d_ws, size_t ws_size,
                              hipStream_t stream) {
    const float* logits  = (const float*)d_in[0];
    const float* pboxes  = (const float*)d_in[1];
    const int*   tlabels = (const int*)d_in[2];
    const float* tboxes  = (const float*)d_in[3];
    float* out = (float*)d_out;

    fused_kernel<<<BS + NCOSTBLK, LT, 0, stream>>>(
        logits, pboxes, tlabels, tboxes,
        out, out + C3_SZ, out + C3_SZ + (size_t)BS * NT);
}